// Round 4
// baseline (293.296 us; speedup 1.0000x reference)
//
#include <hip/hip_runtime.h>
#include <math.h>

// ---------------------------------------------------------------------------
// JAX Threefry-2x32 (constexpr for key derivation, device for per-elem hash).
// ---------------------------------------------------------------------------
struct K2 { unsigned a, b; };

__host__ __device__ constexpr unsigned rotl32c(unsigned x, int r) {
  return (x << r) | (x >> (32 - r));
}

__host__ __device__ constexpr K2 threefry2x32(unsigned k0, unsigned k1,
                                              unsigned x0, unsigned x1) {
  const unsigned ks2 = k0 ^ k1 ^ 0x1BD11BDAu;
  const unsigned ks[3] = {k0, k1, ks2};
  const int rotA[4] = {13, 15, 26, 6};
  const int rotB[4] = {17, 29, 16, 24};
  x0 += k0; x1 += k1;
  for (int g = 0; g < 5; ++g) {
    const int* rr = (g & 1) ? rotB : rotA;
    for (int i = 0; i < 4; ++i) {
      x0 += x1;
      x1 = rotl32c(x1, rr[i]);
      x1 ^= x0;
    }
    x0 += ks[(g + 1) % 3];
    x1 += ks[(g + 2) % 3] + (unsigned)(g + 1);
  }
  return K2{x0, x1};
}

__host__ __device__ constexpr K2 hop_key(unsigned k) {
  K2 f = threefry2x32(0u, 42u, 0u, k);
  return threefry2x32(f.a, f.b, 0u, 1u);
}

constexpr K2 HK0 = hop_key(0u);
constexpr K2 HK1 = hop_key(1u);

// ---------------------------------------------------------------------------
// Kernel 1: all sampling + gather-means, fused.
//   blocks 0..2559   : hop-2 sample + 25-row mean -> nm1[m] (m = blk*4+wave),
//                      also computes s1[m] inline and stores it.
//   blocks 0..255    : additionally zero nml1 (for kernel-2 atomics).
//   blocks 2560..2815: hop-1 10-row mean -> nm0[m0] (s1 recomputed inline).
// One wave per output row; float4 per lane; 5-deep load batches.
// ---------------------------------------------------------------------------
__global__ __launch_bounds__(256) void sample_means(
    const int* __restrict__ node_ids, const int* __restrict__ adj,
    const float* __restrict__ feat, int* __restrict__ s1,
    float* __restrict__ nm1, float* __restrict__ nm0,
    float* __restrict__ nml1) {
  const int blk = blockIdx.x;
  const int w = threadIdx.x >> 6;
  const int lane = threadIdx.x & 63;

  if (blk < 256) {  // zero nml1: 1024*256 floats = 65536 float4
    ((float4*)nml1)[blk * 256 + threadIdx.x] = make_float4(0.f, 0.f, 0.f, 0.f);
  }

  if (blk < 2560) {
    const int m = blk * 4 + w;  // 0..10239
    // hop-1 sample for this row (wave-uniform recompute)
    K2 r0 = threefry2x32(HK0.a, HK0.b, 0u, (unsigned)m);
    const int nid = adj[(long long)node_ids[m / 10] * 128 +
                        (int)((r0.a ^ r0.b) & 127u)];
    if (lane == 0) s1[m] = nid;
    // hop-2 samples in lanes 0..24
    int srow;
    {
      unsigned i = (unsigned)(m * 25 + (lane < 25 ? lane : 0));
      K2 r = threefry2x32(HK1.a, HK1.b, 0u, i);
      srow = adj[(long long)nid * 128 + (int)((r.a ^ r.b) & 127u)];
    }
    float4 acc = make_float4(0.f, 0.f, 0.f, 0.f);
#pragma unroll
    for (int c = 0; c < 25; c += 5) {
      float4 v[5];
#pragma unroll
      for (int j = 0; j < 5; ++j) {
        long long row = (long long)__shfl(srow, c + j, 64);
        v[j] = *(const float4*)(feat + row * 256 + (lane << 2));
      }
#pragma unroll
      for (int j = 0; j < 5; ++j) {
        acc.x += v[j].x; acc.y += v[j].y; acc.z += v[j].z; acc.w += v[j].w;
      }
    }
    const float s = 1.f / 25.f;
    acc.x *= s; acc.y *= s; acc.z *= s; acc.w *= s;
    *(float4*)(nm1 + (long long)m * 256 + (lane << 2)) = acc;
  } else {
    const int m0 = (blk - 2560) * 4 + w;  // 0..1023
    // recompute s1[m0*10 + j] inline in lanes 0..9 (same adj row)
    int srow;
    {
      int j = lane < 10 ? lane : 0;
      K2 r = threefry2x32(HK0.a, HK0.b, 0u, (unsigned)(m0 * 10 + j));
      srow = adj[(long long)node_ids[m0] * 128 + (int)((r.a ^ r.b) & 127u)];
    }
    float4 acc = make_float4(0.f, 0.f, 0.f, 0.f);
#pragma unroll
    for (int c = 0; c < 10; c += 5) {
      float4 v[5];
#pragma unroll
      for (int j = 0; j < 5; ++j) {
        long long row = (long long)__shfl(srow, c + j, 64);
        v[j] = *(const float4*)(feat + row * 256 + (lane << 2));
      }
#pragma unroll
      for (int j = 0; j < 5; ++j) {
        acc.x += v[j].x; acc.y += v[j].y; acc.z += v[j].z; acc.w += v[j].w;
      }
    }
    acc.x *= 0.1f; acc.y *= 0.1f; acc.z *= 0.1f; acc.w *= 0.1f;
    *(float4*)(nm0 + (long long)m0 * 256 + (lane << 2)) = acc;
  }
}

// ---------------------------------------------------------------------------
// Kernel 2: layer-0 GEMMs (4 configs, one dispatch, flat 1D decode).
// 64x64 tile, 4x4 micro, BK=16, float4 LDS fragments.
// mode 0: C[r, ccol0+...] = relu(v)            (out0 path)
// mode 1: atomicAdd(C[r/10, ccol0+...], relu(v)*0.1)   (fused mean -> nml1)
// ---------------------------------------------------------------------------
struct GemmCfg {
  const float* A; const int* idx; const float* B; float* C;
  int ccol0; int mtiles; int tiles; int mode;
};
struct GemmCfg4 { GemmCfg c[4]; };

__global__ __launch_bounds__(256) void gemm_relu_multi(GemmCfg4 cfgs) {
  int b = blockIdx.x, z = 0;
  while (z < 3 && b >= cfgs.c[z].tiles) { b -= cfgs.c[z].tiles; ++z; }
  const GemmCfg cfg = cfgs.c[z];
  const int mt = b % cfg.mtiles;
  const int nt = b / cfg.mtiles;

  __shared__ __align__(16) float As[16][68];  // transposed A tile
  __shared__ __align__(16) float Bs[16][68];

  const int t = threadIdx.x;
  const int tx = t & 15, ty = t >> 4;

  const int arow = t >> 2;
  const int ak4 = (t & 3) << 2;
  const int grow = mt * 64 + arow;
  const long long asrc = cfg.idx ? (long long)cfg.idx[grow] : (long long)grow;
  const float* Ap = cfg.A + asrc * 256 + ak4;

  const int bkk = t >> 4;
  const int bn4 = (t & 15) << 2;
  const float* Bp = cfg.B + bkk * 128 + nt * 64 + bn4;

  float acc[4][4] = {};

  for (int k0 = 0; k0 < 256; k0 += 16) {
    float4 av = *(const float4*)(Ap + k0);
    float4 bv = *(const float4*)(Bp + (long long)k0 * 128);
    __syncthreads();
    As[ak4 + 0][arow] = av.x;
    As[ak4 + 1][arow] = av.y;
    As[ak4 + 2][arow] = av.z;
    As[ak4 + 3][arow] = av.w;
    *(float4*)&Bs[bkk][bn4] = bv;
    __syncthreads();
#pragma unroll
    for (int kk = 0; kk < 16; ++kk) {
      float4 a = *(const float4*)&As[kk][ty << 2];
      float4 b4 = *(const float4*)&Bs[kk][tx << 2];
      acc[0][0] += a.x * b4.x; acc[0][1] += a.x * b4.y; acc[0][2] += a.x * b4.z; acc[0][3] += a.x * b4.w;
      acc[1][0] += a.y * b4.x; acc[1][1] += a.y * b4.y; acc[1][2] += a.y * b4.z; acc[1][3] += a.y * b4.w;
      acc[2][0] += a.z * b4.x; acc[2][1] += a.z * b4.y; acc[2][2] += a.z * b4.z; acc[2][3] += a.z * b4.w;
      acc[3][0] += a.w * b4.x; acc[3][1] += a.w * b4.y; acc[3][2] += a.w * b4.z; acc[3][3] += a.w * b4.w;
    }
  }

  if (cfg.mode == 0) {
#pragma unroll
    for (int i = 0; i < 4; ++i) {
      const int r = mt * 64 + (ty << 2) + i;
      float* Cp = cfg.C + (long long)r * 256 + cfg.ccol0 + nt * 64 + (tx << 2);
#pragma unroll
      for (int j = 0; j < 4; ++j) {
        float v = acc[i][j];
        Cp[j] = v > 0.f ? v : 0.f;
      }
    }
  } else {
#pragma unroll
    for (int i = 0; i < 4; ++i) {
      const int r = mt * 64 + (ty << 2) + i;
      float* Cp = cfg.C + (long long)(r / 10) * 256 + cfg.ccol0 + nt * 64 + (tx << 2);
#pragma unroll
      for (int j = 0; j < 4; ++j) {
        float v = acc[i][j];
        atomicAdd(&Cp[j], (v > 0.f ? v : 0.f) * 0.1f);
      }
    }
  }
}

// ---------------------------------------------------------------------------
// Kernel 3: layer-1 (both GEMMs) + l2-normalize + Dense(1), fused.
// 64 blocks x 16 rows. A = [out0 | nml1] staged in LDS; W streamed per k-slab.
// Thread (m = t/16, cb = t%16) computes 16 output cols of row m.
// ---------------------------------------------------------------------------
__global__ __launch_bounds__(256) void layer1_final(
    const float* __restrict__ out0, const float* __restrict__ nml1,
    const float* __restrict__ ws1, const float* __restrict__ wn1,
    const float* __restrict__ w_out, const float* __restrict__ b_out,
    float* __restrict__ out) {
  __shared__ __align__(16) float As[16][520];  // [row][0:256 out0 | 256:512 nml1]
  __shared__ __align__(16) float Bs[16][260];  // k-slab of [w_self_1 | w_neigh_1]
  __shared__ __align__(16) float Hs[16][260];  // relu'd hidden for reduction

  const int t = threadIdx.x;
  const int r0 = blockIdx.x * 16;

  // stage A (2048 float4): flat f = t + 256*i; row = f/128, c4 = f%128
#pragma unroll
  for (int i = 0; i < 8; ++i) {
    const int f = t + (i << 8);
    const int row = f >> 7, c4 = f & 127;
    const float* src = (c4 < 64)
        ? out0 + (long long)(r0 + row) * 256 + (c4 << 2)
        : nml1 + (long long)(r0 + row) * 256 + ((c4 - 64) << 2);
    *(float4*)&As[row][c4 << 2] = *(const float4*)src;
  }

  const int m = t >> 4;
  const int cb = t & 15;
  const int aoff = (cb < 8) ? 0 : 256;

  const int skk = t >> 4;
  const int sc = (t & 15) << 4;
  const float* bbase = (sc < 128) ? ws1 + sc : wn1 + (sc - 128);

  float acc[16] = {};

  for (int k0 = 0; k0 < 256; k0 += 16) {
    const float* bsrc = bbase + (k0 + skk) * 128;
    __syncthreads();
#pragma unroll
    for (int u = 0; u < 4; ++u)
      *(float4*)&Bs[skk][sc + (u << 2)] = *(const float4*)(bsrc + (u << 2));
    __syncthreads();
#pragma unroll
    for (int q = 0; q < 16; ++q) {
      const float a = As[m][aoff + k0 + q];
#pragma unroll
      for (int j4 = 0; j4 < 4; ++j4) {
        float4 b4 = *(const float4*)&Bs[q][(cb << 4) + (j4 << 2)];
        acc[j4 * 4 + 0] += a * b4.x;
        acc[j4 * 4 + 1] += a * b4.y;
        acc[j4 * 4 + 2] += a * b4.z;
        acc[j4 * 4 + 3] += a * b4.w;
      }
    }
  }

  // relu -> Hs
#pragma unroll
  for (int j4 = 0; j4 < 4; ++j4) {
    float4 h4;
    h4.x = fmaxf(acc[j4 * 4 + 0], 0.f);
    h4.y = fmaxf(acc[j4 * 4 + 1], 0.f);
    h4.z = fmaxf(acc[j4 * 4 + 2], 0.f);
    h4.w = fmaxf(acc[j4 * 4 + 3], 0.f);
    *(float4*)&Hs[m][(cb << 4) + (j4 << 2)] = h4;
  }
  __syncthreads();

  // reduction: wave wv handles rows 4*wv .. 4*wv+3
  const int wv = t >> 6, lane = t & 63;
  for (int rr = 0; rr < 4; ++rr) {
    const int row = wv * 4 + rr;
    float4 h4 = *(const float4*)&Hs[row][lane << 2];
    float4 w4 = *(const float4*)&w_out[lane << 2];
    float ss = h4.x * h4.x + h4.y * h4.y + h4.z * h4.z + h4.w * h4.w;
    float dd = h4.x * w4.x + h4.y * w4.y + h4.z * w4.z + h4.w * w4.w;
    for (int off = 32; off; off >>= 1) {
      ss += __shfl_down(ss, off, 64);
      dd += __shfl_down(dd, off, 64);
    }
    if (lane == 0)
      out[r0 + row] = dd / sqrtf(fmaxf(ss, 1e-12f)) + b_out[0];
  }
}

// ---------------------------------------------------------------------------
extern "C" void kernel_launch(void* const* d_in, const int* in_sizes, int n_in,
                              void* d_out, int out_size, void* d_ws, size_t ws_size,
                              hipStream_t stream) {
  (void)in_sizes; (void)n_in; (void)out_size; (void)ws_size;

  const float* features  = (const float*)d_in[0];  // [100000,256]
  const float* w_self_0  = (const float*)d_in[1];  // [256,128]
  const float* w_neigh_0 = (const float*)d_in[2];  // [256,128]
  const float* w_self_1  = (const float*)d_in[3];  // [256,128]
  const float* w_neigh_1 = (const float*)d_in[4];  // [256,128]
  const float* w_out     = (const float*)d_in[5];  // [256,1]
  const float* b_out     = (const float*)d_in[6];  // [1]
  const int*   node_ids  = (const int*)d_in[7];    // [1024]
  const int*   adj       = (const int*)d_in[8];    // [100000,128]
  float* out = (float*)d_out;                      // [1024]

  char* ws = (char*)d_ws;
  size_t off = 0;
  auto alloc = [&](size_t bytes) -> void* {
    void* p = ws + off;
    off = (off + bytes + 255) & ~(size_t)255;
    return p;
  };
  int*   s1   = (int*)alloc(10240 * sizeof(int));
  float* nm1  = (float*)alloc((size_t)10240 * 256 * 4);  // hop-2 neighbor means
  float* nm0  = (float*)alloc((size_t)1024 * 256 * 4);   // hop-1 neighbor means
  float* out0 = (float*)alloc((size_t)1024 * 256 * 4);   // layer-0 hop-0 hidden
  float* nml1 = (float*)alloc((size_t)1024 * 256 * 4);   // layer-1 neighbor mean (atomic)

  // 1) all sampling + gather means (+ nml1 zeroing)
  sample_means<<<2816, 256, 0, stream>>>(node_ids, adj, features, s1, nm1, nm0, nml1);

  // 2) layer-0 GEMMs; self/neigh hop-1 paths accumulate straight into nml1
  {
    GemmCfg4 cf;
    cf.c[0] = {features, s1,       w_self_0,  nml1, 0,   160, 320, 1};
    cf.c[1] = {nm1,      nullptr,  w_neigh_0, nml1, 128, 160, 320, 1};
    cf.c[2] = {features, node_ids, w_self_0,  out0, 0,   16,  32,  0};
    cf.c[3] = {nm0,      nullptr,  w_neigh_0, out0, 128, 16,  32,  0};
    gemm_relu_multi<<<704, 256, 0, stream>>>(cf);
  }

  // 3) layer-1 + l2-normalize + Dense(1)
  layer1_final<<<64, 256, 0, stream>>>(out0, nml1, w_self_1, w_neigh_1,
                                       w_out, b_out, out);
}

// Round 5
// 268.636 us; speedup vs baseline: 1.0918x; 1.0918x over previous
//
#include <hip/hip_runtime.h>
#include <math.h>

// ---------------------------------------------------------------------------
// JAX Threefry-2x32 (constexpr for key derivation, device for per-elem hash).
// ---------------------------------------------------------------------------
struct K2 { unsigned a, b; };

__host__ __device__ constexpr unsigned rotl32c(unsigned x, int r) {
  return (x << r) | (x >> (32 - r));
}

__host__ __device__ constexpr K2 threefry2x32(unsigned k0, unsigned k1,
                                              unsigned x0, unsigned x1) {
  const unsigned ks2 = k0 ^ k1 ^ 0x1BD11BDAu;
  const unsigned ks[3] = {k0, k1, ks2};
  const int rotA[4] = {13, 15, 26, 6};
  const int rotB[4] = {17, 29, 16, 24};
  x0 += k0; x1 += k1;
  for (int g = 0; g < 5; ++g) {
    const int* rr = (g & 1) ? rotB : rotA;
    for (int i = 0; i < 4; ++i) {
      x0 += x1;
      x1 = rotl32c(x1, rr[i]);
      x1 ^= x0;
    }
    x0 += ks[(g + 1) % 3];
    x1 += ks[(g + 2) % 3] + (unsigned)(g + 1);
  }
  return K2{x0, x1};
}

__host__ __device__ constexpr K2 hop_key(unsigned k) {
  K2 f = threefry2x32(0u, 42u, 0u, k);
  return threefry2x32(f.a, f.b, 0u, 1u);
}

constexpr K2 HK0 = hop_key(0u);
constexpr K2 HK1 = hop_key(1u);

// ---------------------------------------------------------------------------
// Kernel 1: all sampling + gather-means, fused (NO atomics).
//   blocks 0..2559   : hop-2 sample + 25-row mean -> nm1[m], stores s1[m].
//   blocks 2560..2815: hop-1 10-row mean -> nm0[m0] (s1 recomputed inline).
// One wave per output row; float4 per lane; 5-deep load batches.
// ---------------------------------------------------------------------------
__global__ __launch_bounds__(256) void sample_means(
    const int* __restrict__ node_ids, const int* __restrict__ adj,
    const float* __restrict__ feat, int* __restrict__ s1,
    float* __restrict__ nm1, float* __restrict__ nm0) {
  const int blk = blockIdx.x;
  const int w = threadIdx.x >> 6;
  const int lane = threadIdx.x & 63;

  if (blk < 2560) {
    const int m = blk * 4 + w;  // 0..10239
    // hop-1 sample for this row (wave-uniform recompute)
    K2 r0 = threefry2x32(HK0.a, HK0.b, 0u, (unsigned)m);
    const int nid = adj[(long long)node_ids[m / 10] * 128 +
                        (int)((r0.a ^ r0.b) & 127u)];
    if (lane == 0) s1[m] = nid;
    // hop-2 samples in lanes 0..24
    int srow;
    {
      unsigned i = (unsigned)(m * 25 + (lane < 25 ? lane : 0));
      K2 r = threefry2x32(HK1.a, HK1.b, 0u, i);
      srow = adj[(long long)nid * 128 + (int)((r.a ^ r.b) & 127u)];
    }
    float4 acc = make_float4(0.f, 0.f, 0.f, 0.f);
#pragma unroll
    for (int c = 0; c < 25; c += 5) {
      float4 v[5];
#pragma unroll
      for (int j = 0; j < 5; ++j) {
        long long row = (long long)__shfl(srow, c + j, 64);
        v[j] = *(const float4*)(feat + row * 256 + (lane << 2));
      }
#pragma unroll
      for (int j = 0; j < 5; ++j) {
        acc.x += v[j].x; acc.y += v[j].y; acc.z += v[j].z; acc.w += v[j].w;
      }
    }
    const float s = 1.f / 25.f;
    acc.x *= s; acc.y *= s; acc.z *= s; acc.w *= s;
    *(float4*)(nm1 + (long long)m * 256 + (lane << 2)) = acc;
  } else {
    const int m0 = (blk - 2560) * 4 + w;  // 0..1023
    int srow;
    {
      int j = lane < 10 ? lane : 0;
      K2 r = threefry2x32(HK0.a, HK0.b, 0u, (unsigned)(m0 * 10 + j));
      srow = adj[(long long)node_ids[m0] * 128 + (int)((r.a ^ r.b) & 127u)];
    }
    float4 acc = make_float4(0.f, 0.f, 0.f, 0.f);
#pragma unroll
    for (int c = 0; c < 10; c += 5) {
      float4 v[5];
#pragma unroll
      for (int j = 0; j < 5; ++j) {
        long long row = (long long)__shfl(srow, c + j, 64);
        v[j] = *(const float4*)(feat + row * 256 + (lane << 2));
      }
#pragma unroll
      for (int j = 0; j < 5; ++j) {
        acc.x += v[j].x; acc.y += v[j].y; acc.z += v[j].z; acc.w += v[j].w;
      }
    }
    acc.x *= 0.1f; acc.y *= 0.1f; acc.z *= 0.1f; acc.w *= 0.1f;
    *(float4*)(nm0 + (long long)m0 * 256 + (lane << 2)) = acc;
  }
}

// ---------------------------------------------------------------------------
// Kernel 2: layer-0 GEMMs (4 configs, one dispatch, flat 1D decode).
// 64x64 tile, 4x4 micro, BK=16, float4 LDS fragments (round-2 proven loop).
// C[m, ccol0 + nt*64 + n] = relu(A[row(m)] @ B[:, nt*64+n])
// ---------------------------------------------------------------------------
struct GemmCfg {
  const float* A; const int* idx; const float* B; float* C;
  int ccol0; int mtiles; int tiles;
};
struct GemmCfg4 { GemmCfg c[4]; };

__global__ __launch_bounds__(256) void gemm_relu_multi(GemmCfg4 cfgs) {
  int b = blockIdx.x, z = 0;
  while (z < 3 && b >= cfgs.c[z].tiles) { b -= cfgs.c[z].tiles; ++z; }
  const GemmCfg cfg = cfgs.c[z];
  const int mt = b % cfg.mtiles;
  const int nt = b / cfg.mtiles;

  __shared__ __align__(16) float As[16][68];  // transposed A tile, padded
  __shared__ __align__(16) float Bs[16][68];

  const int t = threadIdx.x;
  const int tx = t & 15, ty = t >> 4;

  const int arow = t >> 2;
  const int ak4 = (t & 3) << 2;
  const int grow = mt * 64 + arow;
  const long long asrc = cfg.idx ? (long long)cfg.idx[grow] : (long long)grow;
  const float* Ap = cfg.A + asrc * 256 + ak4;

  const int bkk = t >> 4;
  const int bn4 = (t & 15) << 2;
  const float* Bp = cfg.B + bkk * 128 + nt * 64 + bn4;

  float acc[4][4] = {};

  for (int k0 = 0; k0 < 256; k0 += 16) {
    float4 av = *(const float4*)(Ap + k0);
    float4 bv = *(const float4*)(Bp + (long long)k0 * 128);
    __syncthreads();
    As[ak4 + 0][arow] = av.x;
    As[ak4 + 1][arow] = av.y;
    As[ak4 + 2][arow] = av.z;
    As[ak4 + 3][arow] = av.w;
    *(float4*)&Bs[bkk][bn4] = bv;
    __syncthreads();
#pragma unroll
    for (int kk = 0; kk < 16; ++kk) {
      float4 a = *(const float4*)&As[kk][ty << 2];
      float4 b4 = *(const float4*)&Bs[kk][tx << 2];
      acc[0][0] += a.x * b4.x; acc[0][1] += a.x * b4.y; acc[0][2] += a.x * b4.z; acc[0][3] += a.x * b4.w;
      acc[1][0] += a.y * b4.x; acc[1][1] += a.y * b4.y; acc[1][2] += a.y * b4.z; acc[1][3] += a.y * b4.w;
      acc[2][0] += a.z * b4.x; acc[2][1] += a.z * b4.y; acc[2][2] += a.z * b4.z; acc[2][3] += a.z * b4.w;
      acc[3][0] += a.w * b4.x; acc[3][1] += a.w * b4.y; acc[3][2] += a.w * b4.z; acc[3][3] += a.w * b4.w;
    }
  }

#pragma unroll
  for (int i = 0; i < 4; ++i) {
    const int r = mt * 64 + (ty << 2) + i;
    float* Cp = cfg.C + (long long)r * 256 + cfg.ccol0 + nt * 64 + (tx << 2);
#pragma unroll
    for (int j = 0; j < 4; ++j) {
      float v = acc[i][j];
      Cp[j] = v > 0.f ? v : 0.f;
    }
  }
}

// ---------------------------------------------------------------------------
// Kernel 3: wave-per-row mean of 10 contiguous rows (out1 -> nml1).
// ---------------------------------------------------------------------------
template <int S>
__global__ __launch_bounds__(256) void mean_rows_w(
    const float* __restrict__ src, float* __restrict__ dst, float invS) {
  const int m = blockIdx.x * 4 + (threadIdx.x >> 6);
  const int lane = threadIdx.x & 63;
  const long long base = (long long)m * S;

  float4 acc = make_float4(0.f, 0.f, 0.f, 0.f);
#pragma unroll
  for (int c = 0; c < S; c += 5) {
    float4 v[5];
#pragma unroll
    for (int j = 0; j < 5; ++j)
      v[j] = *(const float4*)(src + (base + c + j) * 256 + (lane << 2));
#pragma unroll
    for (int j = 0; j < 5; ++j) {
      acc.x += v[j].x; acc.y += v[j].y; acc.z += v[j].z; acc.w += v[j].w;
    }
  }
  acc.x *= invS; acc.y *= invS; acc.z *= invS; acc.w *= invS;
  *(float4*)(dst + (long long)m * 256 + (lane << 2)) = acc;
}

// ---------------------------------------------------------------------------
// Kernel 4: layer-1 (both GEMMs) + l2-normalize + Dense(1), fused.
// 64 blocks x 16 rows. A = [out0 | nml1] staged in LDS; W streamed per k-slab.
// ---------------------------------------------------------------------------
__global__ __launch_bounds__(256) void layer1_final(
    const float* __restrict__ out0, const float* __restrict__ nml1,
    const float* __restrict__ ws1, const float* __restrict__ wn1,
    const float* __restrict__ w_out, const float* __restrict__ b_out,
    float* __restrict__ out) {
  __shared__ __align__(16) float As[16][520];  // [row][0:256 out0 | 256:512 nml1]
  __shared__ __align__(16) float Bs[16][260];  // k-slab of [w_self_1 | w_neigh_1]
  __shared__ __align__(16) float Hs[16][260];  // relu'd hidden for reduction

  const int t = threadIdx.x;
  const int r0 = blockIdx.x * 16;

#pragma unroll
  for (int i = 0; i < 8; ++i) {
    const int f = t + (i << 8);
    const int row = f >> 7, c4 = f & 127;
    const float* src = (c4 < 64)
        ? out0 + (long long)(r0 + row) * 256 + (c4 << 2)
        : nml1 + (long long)(r0 + row) * 256 + ((c4 - 64) << 2);
    *(float4*)&As[row][c4 << 2] = *(const float4*)src;
  }

  const int m = t >> 4;
  const int cb = t & 15;
  const int aoff = (cb < 8) ? 0 : 256;

  const int skk = t >> 4;
  const int sc = (t & 15) << 4;
  const float* bbase = (sc < 128) ? ws1 + sc : wn1 + (sc - 128);

  float acc[16] = {};

  for (int k0 = 0; k0 < 256; k0 += 16) {
    const float* bsrc = bbase + (k0 + skk) * 128;
    __syncthreads();
#pragma unroll
    for (int u = 0; u < 4; ++u)
      *(float4*)&Bs[skk][sc + (u << 2)] = *(const float4*)(bsrc + (u << 2));
    __syncthreads();
#pragma unroll
    for (int q = 0; q < 16; ++q) {
      const float a = As[m][aoff + k0 + q];
#pragma unroll
      for (int j4 = 0; j4 < 4; ++j4) {
        float4 b4 = *(const float4*)&Bs[q][(cb << 4) + (j4 << 2)];
        acc[j4 * 4 + 0] += a * b4.x;
        acc[j4 * 4 + 1] += a * b4.y;
        acc[j4 * 4 + 2] += a * b4.z;
        acc[j4 * 4 + 3] += a * b4.w;
      }
    }
  }

#pragma unroll
  for (int j4 = 0; j4 < 4; ++j4) {
    float4 h4;
    h4.x = fmaxf(acc[j4 * 4 + 0], 0.f);
    h4.y = fmaxf(acc[j4 * 4 + 1], 0.f);
    h4.z = fmaxf(acc[j4 * 4 + 2], 0.f);
    h4.w = fmaxf(acc[j4 * 4 + 3], 0.f);
    *(float4*)&Hs[m][(cb << 4) + (j4 << 2)] = h4;
  }
  __syncthreads();

  const int wv = t >> 6, lane = t & 63;
  for (int rr = 0; rr < 4; ++rr) {
    const int row = wv * 4 + rr;
    float4 h4 = *(const float4*)&Hs[row][lane << 2];
    float4 w4 = *(const float4*)&w_out[lane << 2];
    float ss = h4.x * h4.x + h4.y * h4.y + h4.z * h4.z + h4.w * h4.w;
    float dd = h4.x * w4.x + h4.y * w4.y + h4.z * w4.z + h4.w * w4.w;
    for (int off = 32; off; off >>= 1) {
      ss += __shfl_down(ss, off, 64);
      dd += __shfl_down(dd, off, 64);
    }
    if (lane == 0)
      out[r0 + row] = dd / sqrtf(fmaxf(ss, 1e-12f)) + b_out[0];
  }
}

// ---------------------------------------------------------------------------
extern "C" void kernel_launch(void* const* d_in, const int* in_sizes, int n_in,
                              void* d_out, int out_size, void* d_ws, size_t ws_size,
                              hipStream_t stream) {
  (void)in_sizes; (void)n_in; (void)out_size; (void)ws_size;

  const float* features  = (const float*)d_in[0];  // [100000,256]
  const float* w_self_0  = (const float*)d_in[1];  // [256,128]
  const float* w_neigh_0 = (const float*)d_in[2];  // [256,128]
  const float* w_self_1  = (const float*)d_in[3];  // [256,128]
  const float* w_neigh_1 = (const float*)d_in[4];  // [256,128]
  const float* w_out     = (const float*)d_in[5];  // [256,1]
  const float* b_out     = (const float*)d_in[6];  // [1]
  const int*   node_ids  = (const int*)d_in[7];    // [1024]
  const int*   adj       = (const int*)d_in[8];    // [100000,128]
  float* out = (float*)d_out;                      // [1024]

  char* ws = (char*)d_ws;
  size_t off = 0;
  auto alloc = [&](size_t bytes) -> void* {
    void* p = ws + off;
    off = (off + bytes + 255) & ~(size_t)255;
    return p;
  };
  int*   s1   = (int*)alloc(10240 * sizeof(int));
  float* nm1  = (float*)alloc((size_t)10240 * 256 * 4);  // hop-2 neighbor means
  float* nm0  = (float*)alloc((size_t)1024 * 256 * 4);   // hop-1 neighbor means
  float* out1 = (float*)alloc((size_t)10240 * 256 * 4);  // layer-0 hop-1 hidden
  float* out0 = (float*)alloc((size_t)1024 * 256 * 4);   // layer-0 hop-0 hidden
  float* nml1 = (float*)alloc((size_t)1024 * 256 * 4);   // layer-1 neighbor mean

  // 1) all sampling + gather means
  sample_means<<<2816, 256, 0, stream>>>(node_ids, adj, features, s1, nm1, nm0);

  // 2) layer-0 GEMMs (flat decode, 704 blocks)
  {
    GemmCfg4 cf;
    cf.c[0] = {features, s1,       w_self_0,  out1, 0,   160, 320};
    cf.c[1] = {nm1,      nullptr,  w_neigh_0, out1, 128, 160, 320};
    cf.c[2] = {features, node_ids, w_self_0,  out0, 0,   16,  32};
    cf.c[3] = {nm0,      nullptr,  w_neigh_0, out0, 128, 16,  32};
    gemm_relu_multi<<<704, 256, 0, stream>>>(cf);
  }

  // 3) layer-1 neighbor mean
  mean_rows_w<10><<<256, 256, 0, stream>>>(out1, nml1, 0.1f);

  // 4) layer-1 + l2-normalize + Dense(1)
  layer1_final<<<64, 256, 0, stream>>>(out0, nml1, w_self_1, w_neigh_1,
                                       w_out, b_out, out);
}